// Round 1
// baseline (334.751 us; speedup 1.0000x reference)
//
#include <hip/hip_runtime.h>
#include <math.h>

// Problem constants (from reference): x is (C,H,W) = (256,512,512) float32.
// out = 2 * suffix_max_W( suffix_max_H( x ) )
constexpr int C = 256;
constexpr int H = 512;
constexpr int W = 512;

// One block per channel, one thread per column w.
// - colmax register carries the reverse cummax along H (bottom -> top).
// - per row, a 512-wide suffix-max scan along W:
//     intra-wave: shfl butterfly (clamped src lane; max is idempotent so
//                 re-reading lane 63 is harmless and always correct)
//     cross-wave: 8 wave totals in LDS, ping-pong on h&1 -> 1 barrier/row
// - next row's load prefetched before the scan to hide HBM latency.
__global__ __launch_bounds__(512)
void tlc_kernel(const float* __restrict__ x, float* __restrict__ out) {
    const int c    = blockIdx.x;
    const int w    = threadIdx.x;      // 0..511
    const int lane = w & 63;
    const int wid  = w >> 6;           // 0..7

    __shared__ float totals[2][8];

    const float* __restrict__ xc = x   + (size_t)c * H * W;
    float*       __restrict__ oc = out + (size_t)c * H * W;

    float colmax = -INFINITY;
    float nxt = xc[(size_t)(H - 1) * W + w];

    for (int h = H - 1; h >= 0; --h) {
        float cur = nxt;
        if (h > 0) nxt = xc[(size_t)(h - 1) * W + w];  // prefetch next row

        colmax = fmaxf(colmax, cur);   // H suffix-max for this column
        float v = colmax;

        // intra-wave inclusive suffix-max (lane i -> max of lanes i..63)
        #pragma unroll
        for (int off = 1; off < 64; off <<= 1) {
            int src = lane + off;
            if (src > 63) src = 63;
            v = fmaxf(v, __shfl(v, src));
        }

        // cross-wave carry: wave wid needs max of waves wid+1..7
        const int buf = h & 1;
        if (lane == 0) totals[buf][wid] = v;  // lane 0 holds the segment max
        __syncthreads();
        float carry = -INFINITY;
        for (int j = wid + 1; j < 8; ++j)
            carry = fmaxf(carry, totals[buf][j]);
        v = fmaxf(v, carry);

        oc[(size_t)h * W + w] = 2.0f * v;     // coalesced store
    }
}

extern "C" void kernel_launch(void* const* d_in, const int* in_sizes, int n_in,
                              void* d_out, int out_size, void* d_ws, size_t ws_size,
                              hipStream_t stream) {
    const float* x   = (const float*)d_in[0];
    float*       out = (float*)d_out;
    tlc_kernel<<<dim3(C), dim3(W), 0, stream>>>(x, out);
}

// Round 2
// 178.880 us; speedup vs baseline: 1.8714x; 1.8714x over previous
//
#include <hip/hip_runtime.h>
#include <math.h>

// x: (C,H,W) = (256,512,512) f32.  out = 2 * suffix_max_W( suffix_max_H( x ) )
constexpr int C = 256;
constexpr int H = 512;
constexpr int W = 512;
constexpr int R = 16;   // rows per batch (H % R == 0)

// One block per channel, one thread per column.
// Batch R rows per iteration:
//  - prefetch next batch's R loads up-front (16 outstanding loads/thread)
//  - colmax register chain = reverse cummax along H
//  - R independent 6-step shuffle suffix-max scans along W (ILP)
//  - ONE barrier per batch; cross-wave carries via ping-pong LDS totals,
//    read back as float4 broadcasts (conflict-free)
__global__ __launch_bounds__(512)
void tlc_kernel(const float* __restrict__ x, float* __restrict__ out) {
    const int c    = blockIdx.x;
    const int w    = threadIdx.x;      // 0..511 = column
    const int lane = w & 63;
    const int wid  = w >> 6;           // 0..7

    __shared__ float totals[2][R][8];

    const float* __restrict__ xc = x   + (size_t)c * H * W;
    float*       __restrict__ oc = out + (size_t)c * H * W;

    // clamped source lanes for the suffix-max butterfly (loop-invariant)
    int s1  = lane + 1;  if (s1  > 63) s1  = 63;
    int s2  = lane + 2;  if (s2  > 63) s2  = 63;
    int s4  = lane + 4;  if (s4  > 63) s4  = 63;
    int s8  = lane + 8;  if (s8  > 63) s8  = 63;
    int s16 = lane + 16; if (s16 > 63) s16 = 63;
    int s32 = lane + 32; if (s32 > 63) s32 = 63;

    float colmax = -INFINITY;
    float cur[R], nxt[R];

    #pragma unroll
    for (int r = 0; r < R; ++r)
        cur[r] = xc[(size_t)(H - R + r) * W + w];

    for (int hb = H - R; hb >= 0; hb -= R) {
        // issue next batch's loads immediately — they complete under this
        // batch's scan work
        if (hb >= R) {
            #pragma unroll
            for (int r = 0; r < R; ++r)
                nxt[r] = xc[(size_t)(hb - R + r) * W + w];
        }

        // H suffix-max chain (bottom row of batch is r = R-1)
        float v[R];
        #pragma unroll
        for (int r = R - 1; r >= 0; --r) {
            colmax = fmaxf(colmax, cur[r]);
            v[r] = colmax;
        }

        // intra-wave inclusive suffix-max; R independent scans per step
        #pragma unroll
        for (int r = 0; r < R; ++r) v[r] = fmaxf(v[r], __shfl(v[r], s1));
        #pragma unroll
        for (int r = 0; r < R; ++r) v[r] = fmaxf(v[r], __shfl(v[r], s2));
        #pragma unroll
        for (int r = 0; r < R; ++r) v[r] = fmaxf(v[r], __shfl(v[r], s4));
        #pragma unroll
        for (int r = 0; r < R; ++r) v[r] = fmaxf(v[r], __shfl(v[r], s8));
        #pragma unroll
        for (int r = 0; r < R; ++r) v[r] = fmaxf(v[r], __shfl(v[r], s16));
        #pragma unroll
        for (int r = 0; r < R; ++r) v[r] = fmaxf(v[r], __shfl(v[r], s32));

        // publish wave totals (lane 0 holds the whole-wave max after the scan)
        const int buf = (hb >> 4) & 1;   // ping-pong: one barrier per batch
        if (lane == 0) {
            #pragma unroll
            for (int r = 0; r < R; ++r)
                totals[buf][r][wid] = v[r];
        }
        __syncthreads();

        // carry for wave `wid` = max of totals of waves wid+1..7
        #pragma unroll
        for (int r = 0; r < R; ++r) {
            const float4 t0 = *(const float4*)&totals[buf][r][0];
            const float4 t1 = *(const float4*)&totals[buf][r][4];
            float carry = -INFINITY;
            if (wid < 1) carry = fmaxf(carry, t0.y);
            if (wid < 2) carry = fmaxf(carry, t0.z);
            if (wid < 3) carry = fmaxf(carry, t0.w);
            if (wid < 4) carry = fmaxf(carry, t1.x);
            if (wid < 5) carry = fmaxf(carry, t1.y);
            if (wid < 6) carry = fmaxf(carry, t1.z);
            if (wid < 7) carry = fmaxf(carry, t1.w);
            v[r] = fmaxf(v[r], carry);
            oc[(size_t)(hb + r) * W + w] = 2.0f * v[r];
        }

        #pragma unroll
        for (int r = 0; r < R; ++r)
            cur[r] = nxt[r];
    }
}

extern "C" void kernel_launch(void* const* d_in, const int* in_sizes, int n_in,
                              void* d_out, int out_size, void* d_ws, size_t ws_size,
                              hipStream_t stream) {
    const float* x   = (const float*)d_in[0];
    float*       out = (float*)d_out;
    tlc_kernel<<<dim3(C), dim3(W), 0, stream>>>(x, out);
}